// Round 1
// baseline (485.582 us; speedup 1.0000x reference)
//
#include <hip/hip_runtime.h>
#include <math.h>

#define TILE_SZ 16
#define NEARP 0.8f
#define FARP 1000.0f
#define ATHR (1.0f/255.0f)
#define TTHR 0.0001f

// Record layout (16 floats, 64B):
// 0:u 1:v 2:conic_a 3:conic_b 4:conic_c 5:alpha 6:z 7:t0x 8:t1x 9:t0y 10:t1y
// 11:r 12:g 13:b 14,15: pad

__global__ void preprocess_kernel(const float* __restrict__ pc,
                                  const float* __restrict__ feat,
                                  const int* __restrict__ invalid_mask,
                                  const float* __restrict__ K,
                                  const float* __restrict__ qcam,
                                  const float* __restrict__ tcam,
                                  const int* __restrict__ cam_h,
                                  const int* __restrict__ cam_w,
                                  const int* __restrict__ sh_band,
                                  float* __restrict__ recs,
                                  float* __restrict__ keys,
                                  int N)
{
    int i = blockIdx.x * blockDim.x + threadIdx.x;
    if (i >= N) return;

    float fx = K[0], cx = K[2], fy = K[4], cy = K[5];
    int H = cam_h[0], W = cam_w[0];

    // camera quaternion -> R_wc -> R_cw = R_wc^T, t_cw = -R_cw t
    float qx = qcam[0], qy = qcam[1], qz = qcam[2], qw = qcam[3];
    float qn = sqrtf(qx*qx + qy*qy + qz*qz + qw*qw);
    qx /= qn; qy /= qn; qz /= qn; qw /= qn;
    float R00 = 1.f-2.f*(qy*qy+qz*qz), R01 = 2.f*(qx*qy-qw*qz), R02 = 2.f*(qx*qz+qw*qy);
    float R10 = 2.f*(qx*qy+qw*qz), R11 = 1.f-2.f*(qx*qx+qz*qz), R12 = 2.f*(qy*qz-qw*qx);
    float R20 = 2.f*(qx*qz-qw*qy), R21 = 2.f*(qy*qz+qw*qx), R22 = 1.f-2.f*(qx*qx+qy*qy);
    // R_cw = transpose
    float C00 = R00, C01 = R10, C02 = R20;
    float C10 = R01, C11 = R11, C12 = R21;
    float C20 = R02, C21 = R12, C22 = R22;
    float tx = tcam[0], ty = tcam[1], tz = tcam[2];
    float tcx = -(C00*tx + C01*ty + C02*tz);
    float tcy = -(C10*tx + C11*ty + C12*tz);
    float tcz = -(C20*tx + C21*ty + C22*tz);

    float px = pc[i*3+0], py = pc[i*3+1], pz = pc[i*3+2];
    float xc = C00*px + C01*py + C02*pz + tcx;
    float yc = C10*px + C11*py + C12*pz + tcy;
    float zc = C20*px + C21*py + C22*pz + tcz;
    float inv_z = 1.0f / zc;
    float u = fx * xc * inv_z + cx;
    float v = fy * yc * inv_z + cy;

    bool valid = (invalid_mask[i] == 0) && (zc > NEARP) && (zc < FARP)
              && (u > -4.0f*TILE_SZ) && (u < (float)W + 4.0f*TILE_SZ)
              && (v > -4.0f*TILE_SZ) && (v < (float)H + 4.0f*TILE_SZ);

    // per-point gaussian: quat -> Rp, scales
    float q0 = feat[i*56+0], q1 = feat[i*56+1], q2 = feat[i*56+2], q3 = feat[i*56+3];
    float pn = sqrtf(q0*q0 + q1*q1 + q2*q2 + q3*q3);
    q0 /= pn; q1 /= pn; q2 /= pn; q3 /= pn;
    float P00 = 1.f-2.f*(q1*q1+q2*q2), P01 = 2.f*(q0*q1-q3*q2), P02 = 2.f*(q0*q2+q3*q1);
    float P10 = 2.f*(q0*q1+q3*q2), P11 = 1.f-2.f*(q0*q0+q2*q2), P12 = 2.f*(q1*q2-q3*q0);
    float P20 = 2.f*(q0*q2-q3*q1), P21 = 2.f*(q1*q2+q3*q0), P22 = 1.f-2.f*(q0*q0+q1*q1);
    float s0 = expf(feat[i*56+4]), s1 = expf(feat[i*56+5]), s2 = expf(feat[i*56+6]);
    float M00 = P00*s0, M01 = P01*s1, M02 = P02*s2;
    float M10 = P10*s0, M11 = P11*s1, M12 = P12*s2;
    float M20 = P20*s0, M21 = P21*s1, M22 = P22*s2;
    // Sigma = M M^T (symmetric)
    float S00 = M00*M00 + M01*M01 + M02*M02;
    float S01 = M00*M10 + M01*M11 + M02*M12;
    float S02 = M00*M20 + M01*M21 + M02*M22;
    float S11 = M10*M10 + M11*M11 + M12*M12;
    float S12 = M10*M20 + M11*M21 + M12*M22;
    float S22 = M20*M20 + M21*M21 + M22*M22;
    // Sigma_cam = C Sigma C^T
    float T00 = C00*S00 + C01*S01 + C02*S02;
    float T01 = C00*S01 + C01*S11 + C02*S12;
    float T02 = C00*S02 + C01*S12 + C02*S22;
    float T10 = C10*S00 + C11*S01 + C12*S02;
    float T11 = C10*S01 + C11*S11 + C12*S12;
    float T12 = C10*S02 + C11*S12 + C12*S22;
    float T20 = C20*S00 + C21*S01 + C22*S02;
    float T21 = C20*S01 + C21*S11 + C22*S12;
    float T22 = C20*S02 + C21*S12 + C22*S22;
    float G00 = T00*C00 + T01*C01 + T02*C02;
    float G01 = T00*C10 + T01*C11 + T02*C12;
    float G02 = T00*C20 + T01*C21 + T02*C22;
    float G11 = T10*C10 + T11*C11 + T12*C12;
    float G12 = T10*C20 + T11*C21 + T12*C22;
    float G22 = T20*C20 + T21*C21 + T22*C22;
    // J (2x3), cov2d = J G J^T
    float j00 = fx * inv_z;
    float j02 = -fx * xc * inv_z * inv_z;
    float j11 = fy * inv_z;
    float j12 = -fy * yc * inv_z * inv_z;
    float a0 = j00*G00 + j02*G02;
    float a1 = j00*G01 + j02*G12;
    float a2 = j00*G02 + j02*G22;
    float b1 = j11*G11 + j12*G12;
    float b2 = j11*G12 + j12*G22;
    float cov00 = a0*j00 + a2*j02;
    float cov01 = a1*j11 + a2*j12;
    float cov11 = b1*j11 + b2*j12;

    float A = cov00 + 0.3f;
    float B = cov01;
    float Cc = cov11 + 0.3f;
    float det = fmaxf(A*Cc - B*B, 1e-9f);
    float conic_a = Cc / det;
    float conic_b = -B / det;
    float conic_c = A / det;
    float mid = 0.5f * (A + Cc);
    float lam = mid + sqrtf(fmaxf(mid*mid - det, 1e-9f));
    float radii = ceilf(3.0f * sqrtf(lam));

    float aval = feat[i*56+7];
    float alpha = 1.0f / (1.0f + expf(-aval));

    // SH color
    float dnx = px - tx, dny = py - ty, dnz = pz - tz;
    float dn = sqrtf(dnx*dnx + dny*dny + dnz*dnz);
    float dx = dnx/dn, dy = dny/dn, dz = dnz/dn;
    float xx = dx*dx, yy = dy*dy, zz = dz*dz;
    float xy = dx*dy, yz = dy*dz, xz = dx*dz;
    float basis[16];
    basis[0] = 0.28209479177387814f;
    basis[1] = -0.4886025119029199f * dy;
    basis[2] = 0.4886025119029199f * dz;
    basis[3] = -0.4886025119029199f * dx;
    basis[4] = 1.0925484305920792f * xy;
    basis[5] = -1.0925484305920792f * yz;
    basis[6] = 0.31539156525252005f * (2.f*zz - xx - yy);
    basis[7] = -1.0925484305920792f * xz;
    basis[8] = 0.5462742152960396f * (xx - yy);
    basis[9] = -0.5900435899266435f * dy * (3.f*xx - yy);
    basis[10] = 2.890611442640554f * xy * dz;
    basis[11] = -0.4570457994644658f * dy * (4.f*zz - xx - yy);
    basis[12] = 0.3731763325901154f * dz * (2.f*zz - 3.f*xx - 3.f*yy);
    basis[13] = -0.4570457994644658f * dx * (4.f*zz - xx - yy);
    basis[14] = 1.445305721320277f * dz * (xx - yy);
    basis[15] = -0.5900435899266435f * dx * (xx - 3.f*yy);
    int band = sh_band[0];
    int kc = (band + 1) * (band + 1);
    float c0 = 0.f, c1 = 0.f, c2 = 0.f;
#pragma unroll
    for (int j = 0; j < 16; j++) {
        if (j < kc) {
            c0 += basis[j] * feat[i*56 + 8 + 0*16 + j];
            c1 += basis[j] * feat[i*56 + 8 + 1*16 + j];
            c2 += basis[j] * feat[i*56 + 8 + 2*16 + j];
        }
    }
    c0 = fmaxf(c0 + 0.5f, 0.0f);
    c1 = fmaxf(c1 + 0.5f, 0.0f);
    c2 = fmaxf(c2 + 0.5f, 0.0f);

    // tile bounds
    float tiles_x = (float)(W / TILE_SZ);
    float tiles_y = (float)(H / TILE_SZ);
    float t0x = fminf(fmaxf(floorf((u - radii) / TILE_SZ), 0.0f), tiles_x - 1.0f);
    float t1x = fminf(fmaxf(floorf((u + radii) / TILE_SZ), 0.0f), tiles_x - 1.0f);
    float t0y = fminf(fmaxf(floorf((v - radii) / TILE_SZ), 0.0f), tiles_y - 1.0f);
    float t1y = fminf(fmaxf(floorf((v + radii) / TILE_SZ), 0.0f), tiles_y - 1.0f);

    if (!valid) {
        // impossible bounds + zero alpha: reproduces the vld gate exactly
        t0x = 1e30f; t1x = -1e30f; t0y = 1e30f; t1y = -1e30f;
        alpha = 0.0f;
    }

    float* r = recs + (size_t)i * 16;
    r[0] = u; r[1] = v; r[2] = conic_a; r[3] = conic_b; r[4] = conic_c;
    r[5] = alpha; r[6] = zc;
    r[7] = t0x; r[8] = t1x; r[9] = t0y; r[10] = t1y;
    r[11] = c0; r[12] = c1; r[13] = c2; r[14] = 0.f; r[15] = 0.f;

    keys[i] = valid ? zc : INFINITY;
}

// O(N^2) stable rank sort + scatter (N=2048: 4M comparisons, trivial)
__global__ void sort_scatter_kernel(const float* __restrict__ keys,
                                    const float* __restrict__ recs,
                                    float* __restrict__ sorted_recs,
                                    int N)
{
    int i = blockIdx.x * blockDim.x + threadIdx.x;
    if (i >= N) return;
    float ki = keys[i];
    int rank = 0;
    for (int j = 0; j < N; j++) {
        float kj = keys[j];
        rank += (kj < ki) || (kj == ki && j < i);
    }
    const float4* src = (const float4*)(recs + (size_t)i * 16);
    float4* dst = (float4*)(sorted_recs + (size_t)rank * 16);
    dst[0] = src[0]; dst[1] = src[1]; dst[2] = src[2]; dst[3] = src[3];
}

#define CHUNK 256

__global__ void raster_kernel(const float* __restrict__ sorted_recs, int N,
                              const int* __restrict__ cam_h,
                              const int* __restrict__ cam_w,
                              float* __restrict__ out)
{
    int W = cam_w[0], H = cam_h[0];
    int tiles_x = W / TILE_SZ;
    int bx = blockIdx.x % tiles_x;
    int by = blockIdx.x / tiles_x;
    int tx = threadIdx.x % TILE_SZ;
    int ty = threadIdx.x / TILE_SZ;
    int px = bx * TILE_SZ + tx;
    int py = by * TILE_SZ + ty;
    float pxf = (float)px + 0.5f;
    float pyf = (float)py + 0.5f;
    float txf = (float)bx;
    float tyf = (float)by;

    float T = 1.0f;
    float cr = 0.f, cg = 0.f, cb = 0.f;
    float dep = 0.f, acc = 0.f;
    int cnt = 0;
    bool dead = false;

    __shared__ float sp[CHUNK * 16];

    for (int base = 0; base < N; base += CHUNK) {
        int idx = base + (int)threadIdx.x;
        if (idx < N) {
            const float4* src = (const float4*)(sorted_recs + (size_t)idx * 16);
            float4* dst = (float4*)(sp + threadIdx.x * 16);
            dst[0] = src[0]; dst[1] = src[1]; dst[2] = src[2]; dst[3] = src[3];
        } else {
            sp[threadIdx.x*16 + 5] = 0.0f;   // alpha
            sp[threadIdx.x*16 + 7] = 1e30f;  // t0x
            sp[threadIdx.x*16 + 8] = -1e30f; // t1x
            sp[threadIdx.x*16 + 9] = 1e30f;  // t0y
            sp[threadIdx.x*16 + 10] = -1e30f;// t1y
        }
        __syncthreads();

        if (!dead) {
            int lim = min(CHUNK, N - base);
            for (int j = 0; j < lim; j++) {
                const float* p = sp + j * 16;
                float t0x = p[7], t1x = p[8], t0y = p[9], t1y = p[10];
                // block-uniform tile cull
                if (txf < t0x || txf > t1x || tyf < t0y || tyf > t1y) continue;
                float du = pxf - p[0];
                float dv = pyf - p[1];
                float power = -0.5f * (p[2]*du*du + p[4]*dv*dv) - p[3]*du*dv;
                float ai = fminf(p[5] * expf(fminf(power, 0.0f)), 0.99f);
                if (ai >= ATHR) {
                    float w = T * ai;
                    cr += w * p[11];
                    cg += w * p[12];
                    cb += w * p[13];
                    dep += w * p[6];
                    acc += w;
                    cnt++;
                    T *= (1.0f - ai);
                    if (T <= TTHR) { dead = true; break; }
                }
            }
        }
        int alldone = __syncthreads_and(dead ? 1 : 0);
        if (alldone) break;
    }

    int pix = py * W + px;
    int HW = H * W;
    out[pix*3 + 0] = cr;
    out[pix*3 + 1] = cg;
    out[pix*3 + 2] = cb;
    out[HW*3 + pix] = dep / fmaxf(acc, 1e-6f);
    out[HW*4 + pix] = (float)cnt;
}

extern "C" void kernel_launch(void* const* d_in, const int* in_sizes, int n_in,
                              void* d_out, int out_size, void* d_ws, size_t ws_size,
                              hipStream_t stream) {
    const float* pc    = (const float*)d_in[0];
    const float* feat  = (const float*)d_in[1];
    // d_in[2] point_object_id: unused by the reference
    const int*   inval = (const int*)d_in[3];
    const float* K     = (const float*)d_in[4];
    const float* qc    = (const float*)d_in[5];
    const float* tc    = (const float*)d_in[6];
    const int*   camH  = (const int*)d_in[7];
    const int*   camW  = (const int*)d_in[8];
    const int*   band  = (const int*)d_in[9];
    float* out = (float*)d_out;

    int N = in_sizes[0] / 3;
    // out_size = H*W*5 ; setup uses a square image
    int side = (int)(sqrt((double)(out_size / 5)) + 0.5);
    int H = side, W = side;

    float* recs = (float*)d_ws;
    float* keys = recs + (size_t)N * 16;
    size_t keys_rounded = ((size_t)N + 3) & ~(size_t)3;
    float* sorted_recs = keys + keys_rounded;

    int threads = 256;
    int pblocks = (N + threads - 1) / threads;
    preprocess_kernel<<<pblocks, threads, 0, stream>>>(
        pc, feat, inval, K, qc, tc, camH, camW, band, recs, keys, N);
    sort_scatter_kernel<<<pblocks, threads, 0, stream>>>(keys, recs, sorted_recs, N);

    int tiles = (W / TILE_SZ) * (H / TILE_SZ);
    raster_kernel<<<tiles, threads, 0, stream>>>(sorted_recs, N, camH, camW, out);
}

// Round 2
// 105.254 us; speedup vs baseline: 4.6134x; 4.6134x over previous
//
#include <hip/hip_runtime.h>
#include <math.h>

#define TILE_SZ 16
#define NEARP 0.8f
#define FARP 1000.0f
#define ATHR (1.0f/255.0f)
#define TTHR 0.0001f

// Record layout (16 floats, 64B), float4-aligned groups:
//  [0]=u    [1]=v     [2]=conic_a [3]=conic_b
//  [4]=conic_c [5]=alpha [6]=z    [7]=color_r
//  [8]=color_g [9]=color_b [10]=pad [11]=pad
//  [12]=t0x [13]=t1x  [14]=t0y    [15]=t1y     <- bounds as one float4

__global__ void preprocess_kernel(const float* __restrict__ pc,
                                  const float* __restrict__ feat,
                                  const int* __restrict__ invalid_mask,
                                  const float* __restrict__ K,
                                  const float* __restrict__ qcam,
                                  const float* __restrict__ tcam,
                                  const int* __restrict__ cam_h,
                                  const int* __restrict__ cam_w,
                                  const int* __restrict__ sh_band,
                                  float* __restrict__ recs,
                                  float* __restrict__ keys,
                                  int N)
{
    int i = blockIdx.x * blockDim.x + threadIdx.x;
    if (i >= N) return;

    float fx = K[0], cx = K[2], fy = K[4], cy = K[5];
    int H = cam_h[0], W = cam_w[0];

    float qx = qcam[0], qy = qcam[1], qz = qcam[2], qw = qcam[3];
    float qn = sqrtf(qx*qx + qy*qy + qz*qz + qw*qw);
    qx /= qn; qy /= qn; qz /= qn; qw /= qn;
    float R00 = 1.f-2.f*(qy*qy+qz*qz), R01 = 2.f*(qx*qy-qw*qz), R02 = 2.f*(qx*qz+qw*qy);
    float R10 = 2.f*(qx*qy+qw*qz), R11 = 1.f-2.f*(qx*qx+qz*qz), R12 = 2.f*(qy*qz-qw*qx);
    float R20 = 2.f*(qx*qz-qw*qy), R21 = 2.f*(qy*qz+qw*qx), R22 = 1.f-2.f*(qx*qx+qy*qy);
    float C00 = R00, C01 = R10, C02 = R20;
    float C10 = R01, C11 = R11, C12 = R21;
    float C20 = R02, C21 = R12, C22 = R22;
    float tx = tcam[0], ty = tcam[1], tz = tcam[2];
    float tcx = -(C00*tx + C01*ty + C02*tz);
    float tcy = -(C10*tx + C11*ty + C12*tz);
    float tcz = -(C20*tx + C21*ty + C22*tz);

    float px = pc[i*3+0], py = pc[i*3+1], pz = pc[i*3+2];
    float xc = C00*px + C01*py + C02*pz + tcx;
    float yc = C10*px + C11*py + C12*pz + tcy;
    float zc = C20*px + C21*py + C22*pz + tcz;
    float inv_z = 1.0f / zc;
    float u = fx * xc * inv_z + cx;
    float v = fy * yc * inv_z + cy;

    bool valid = (invalid_mask[i] == 0) && (zc > NEARP) && (zc < FARP)
              && (u > -4.0f*TILE_SZ) && (u < (float)W + 4.0f*TILE_SZ)
              && (v > -4.0f*TILE_SZ) && (v < (float)H + 4.0f*TILE_SZ);

    float q0 = feat[i*56+0], q1 = feat[i*56+1], q2 = feat[i*56+2], q3 = feat[i*56+3];
    float pn = sqrtf(q0*q0 + q1*q1 + q2*q2 + q3*q3);
    q0 /= pn; q1 /= pn; q2 /= pn; q3 /= pn;
    float P00 = 1.f-2.f*(q1*q1+q2*q2), P01 = 2.f*(q0*q1-q3*q2), P02 = 2.f*(q0*q2+q3*q1);
    float P10 = 2.f*(q0*q1+q3*q2), P11 = 1.f-2.f*(q0*q0+q2*q2), P12 = 2.f*(q1*q2-q3*q0);
    float P20 = 2.f*(q0*q2-q3*q1), P21 = 2.f*(q1*q2+q3*q0), P22 = 1.f-2.f*(q0*q0+q1*q1);
    float s0 = expf(feat[i*56+4]), s1 = expf(feat[i*56+5]), s2 = expf(feat[i*56+6]);
    float M00 = P00*s0, M01 = P01*s1, M02 = P02*s2;
    float M10 = P10*s0, M11 = P11*s1, M12 = P12*s2;
    float M20 = P20*s0, M21 = P21*s1, M22 = P22*s2;
    float S00 = M00*M00 + M01*M01 + M02*M02;
    float S01 = M00*M10 + M01*M11 + M02*M12;
    float S02 = M00*M20 + M01*M21 + M02*M22;
    float S11 = M10*M10 + M11*M11 + M12*M12;
    float S12 = M10*M20 + M11*M21 + M12*M22;
    float S22 = M20*M20 + M21*M21 + M22*M22;
    float T00 = C00*S00 + C01*S01 + C02*S02;
    float T01 = C00*S01 + C01*S11 + C02*S12;
    float T02 = C00*S02 + C01*S12 + C02*S22;
    float T10 = C10*S00 + C11*S01 + C12*S02;
    float T11 = C10*S01 + C11*S11 + C12*S12;
    float T12 = C10*S02 + C11*S12 + C12*S22;
    float T20 = C20*S00 + C21*S01 + C22*S02;
    float T21 = C20*S01 + C21*S11 + C22*S12;
    float T22 = C20*S02 + C21*S12 + C22*S22;
    float G00 = T00*C00 + T01*C01 + T02*C02;
    float G01 = T00*C10 + T01*C11 + T02*C12;
    float G02 = T00*C20 + T01*C21 + T02*C22;
    float G11 = T10*C10 + T11*C11 + T12*C12;
    float G12 = T10*C20 + T11*C21 + T12*C22;
    float G22 = T20*C20 + T21*C21 + T22*C22;
    float j00 = fx * inv_z;
    float j02 = -fx * xc * inv_z * inv_z;
    float j11 = fy * inv_z;
    float j12 = -fy * yc * inv_z * inv_z;
    float a0 = j00*G00 + j02*G02;
    float a1 = j00*G01 + j02*G12;
    float a2 = j00*G02 + j02*G22;
    float b1 = j11*G11 + j12*G12;
    float b2 = j11*G12 + j12*G22;
    float cov00 = a0*j00 + a2*j02;
    float cov01 = a1*j11 + a2*j12;
    float cov11 = b1*j11 + b2*j12;

    float A = cov00 + 0.3f;
    float B = cov01;
    float Cc = cov11 + 0.3f;
    float det = fmaxf(A*Cc - B*B, 1e-9f);
    float conic_a = Cc / det;
    float conic_b = -B / det;
    float conic_c = A / det;
    float mid = 0.5f * (A + Cc);
    float lam = mid + sqrtf(fmaxf(mid*mid - det, 1e-9f));
    float radii = ceilf(3.0f * sqrtf(lam));

    float aval = feat[i*56+7];
    float alpha = 1.0f / (1.0f + expf(-aval));

    float dnx = px - tx, dny = py - ty, dnz = pz - tz;
    float dn = sqrtf(dnx*dnx + dny*dny + dnz*dnz);
    float dx = dnx/dn, dy = dny/dn, dz = dnz/dn;
    float xx = dx*dx, yy = dy*dy, zz = dz*dz;
    float xy = dx*dy, yz = dy*dz, xz = dx*dz;
    float basis[16];
    basis[0] = 0.28209479177387814f;
    basis[1] = -0.4886025119029199f * dy;
    basis[2] = 0.4886025119029199f * dz;
    basis[3] = -0.4886025119029199f * dx;
    basis[4] = 1.0925484305920792f * xy;
    basis[5] = -1.0925484305920792f * yz;
    basis[6] = 0.31539156525252005f * (2.f*zz - xx - yy);
    basis[7] = -1.0925484305920792f * xz;
    basis[8] = 0.5462742152960396f * (xx - yy);
    basis[9] = -0.5900435899266435f * dy * (3.f*xx - yy);
    basis[10] = 2.890611442640554f * xy * dz;
    basis[11] = -0.4570457994644658f * dy * (4.f*zz - xx - yy);
    basis[12] = 0.3731763325901154f * dz * (2.f*zz - 3.f*xx - 3.f*yy);
    basis[13] = -0.4570457994644658f * dx * (4.f*zz - xx - yy);
    basis[14] = 1.445305721320277f * dz * (xx - yy);
    basis[15] = -0.5900435899266435f * dx * (xx - 3.f*yy);
    int band = sh_band[0];
    int kc = (band + 1) * (band + 1);
    float c0 = 0.f, c1 = 0.f, c2 = 0.f;
#pragma unroll
    for (int j = 0; j < 16; j++) {
        if (j < kc) {
            c0 += basis[j] * feat[i*56 + 8 + 0*16 + j];
            c1 += basis[j] * feat[i*56 + 8 + 1*16 + j];
            c2 += basis[j] * feat[i*56 + 8 + 2*16 + j];
        }
    }
    c0 = fmaxf(c0 + 0.5f, 0.0f);
    c1 = fmaxf(c1 + 0.5f, 0.0f);
    c2 = fmaxf(c2 + 0.5f, 0.0f);

    float tiles_x = (float)(W / TILE_SZ);
    float tiles_y = (float)(H / TILE_SZ);
    float t0x = fminf(fmaxf(floorf((u - radii) / TILE_SZ), 0.0f), tiles_x - 1.0f);
    float t1x = fminf(fmaxf(floorf((u + radii) / TILE_SZ), 0.0f), tiles_x - 1.0f);
    float t0y = fminf(fmaxf(floorf((v - radii) / TILE_SZ), 0.0f), tiles_y - 1.0f);
    float t1y = fminf(fmaxf(floorf((v + radii) / TILE_SZ), 0.0f), tiles_y - 1.0f);

    if (!valid) {
        t0x = 1e30f; t1x = -1e30f; t0y = 1e30f; t1y = -1e30f;
        alpha = 0.0f;
    }

    float* r = recs + (size_t)i * 16;
    r[0] = u;  r[1] = v;  r[2] = conic_a; r[3] = conic_b;
    r[4] = conic_c; r[5] = alpha; r[6] = zc; r[7] = c0;
    r[8] = c1; r[9] = c2; r[10] = 0.f; r[11] = 0.f;
    r[12] = t0x; r[13] = t1x; r[14] = t0y; r[15] = t1y;

    keys[i] = valid ? zc : INFINITY;
}

// rank sort with LDS-staged keys
#define SORT_STAGE 1024
__global__ void sort_scatter_kernel(const float* __restrict__ keys,
                                    const float* __restrict__ recs,
                                    float* __restrict__ sorted_recs,
                                    int N)
{
    __shared__ float sk[SORT_STAGE];
    int tid = threadIdx.x;
    int i = blockIdx.x * blockDim.x + tid;
    float ki = (i < N) ? keys[i] : 0.0f;
    int rank = 0;
    for (int base = 0; base < N; base += SORT_STAGE) {
        int m = min(SORT_STAGE, N - base);
        for (int t = tid; t < m; t += blockDim.x) sk[t] = keys[base + t];
        __syncthreads();
        if (i < N) {
            for (int j = 0; j < m; j++) {
                float kj = sk[j];
                rank += (kj < ki) || (kj == ki && (base + j) < i);
            }
        }
        __syncthreads();
    }
    if (i < N) {
        const float4* src = (const float4*)(recs + (size_t)i * 16);
        float4* dst = (float4*)(sorted_recs + (size_t)rank * 16);
        dst[0] = src[0]; dst[1] = src[1]; dst[2] = src[2]; dst[3] = src[3];
    }
}

#define LIST_CAP 4096

__global__ void raster_kernel(const float* __restrict__ sorted_recs, int N,
                              const int* __restrict__ cam_h,
                              const int* __restrict__ cam_w,
                              float* __restrict__ out)
{
    int W = cam_w[0], H = cam_h[0];
    int tiles_x = W / TILE_SZ;
    int bx = blockIdx.x % tiles_x;
    int by = blockIdx.x / tiles_x;
    int tid = threadIdx.x;
    int lane = tid & 63;
    int wv = tid >> 6;
    int tx = tid % TILE_SZ;
    int ty = tid / TILE_SZ;
    int px = bx * TILE_SZ + tx;
    int py = by * TILE_SZ + ty;
    float pxf = (float)px + 0.5f;
    float pyf = (float)py + 0.5f;
    float txf = (float)bx;
    float tyf = (float)by;

    float T = 1.0f;
    float cr = 0.f, cg = 0.f, cb = 0.f;
    float dep = 0.f, acc = 0.f;
    int cnt_px = 0;

    __shared__ float4 sp4[256];           // 64 staged records (4KB)
    float* sp = (float*)sp4;
    __shared__ unsigned short list[LIST_CAP]; // 8KB
    __shared__ int wcnt[4];

    bool alldead = false;

    for (int seg = 0; seg < N && !alldead; seg += LIST_CAP) {
        int segN = min(LIST_CAP, N - seg);
        int rounds = (segN + 255) / 256;

        // Phase 1a: membership predicates (independent loads -> pipelined)
        unsigned pmask = 0;
        for (int r = 0; r < rounds; r++) {
            int idx = seg + r * 256 + tid;
            bool pred = false;
            if (idx < N) {
                float4 b = *(const float4*)(sorted_recs + (size_t)idx * 16 + 12);
                pred = (txf >= b.x) && (txf <= b.y) && (tyf >= b.z) && (tyf <= b.w);
            }
            pmask |= ((unsigned)pred) << r;
        }

        // Phase 1b: order-preserving compaction into LDS list
        int cnt = 0;
        for (int r = 0; r < rounds; r++) {
            bool pred = (pmask >> r) & 1u;
            unsigned long long m = __ballot(pred);
            if (lane == 0) wcnt[wv] = __popcll(m);
            __syncthreads();
            int off = cnt;
            for (int w = 0; w < wv; w++) off += wcnt[w];
            int tot = wcnt[0] + wcnt[1] + wcnt[2] + wcnt[3];
            if (pred) {
                int below = __popcll(m & ((1ull << lane) - 1ull));
                list[off + below] = (unsigned short)(r * 256 + tid);
            }
            cnt += tot;
            __syncthreads();
        }

        // Phase 2: composite over compacted list, 64 records per chunk
        for (int c = 0; c < cnt && !alldead; c += 64) {
            int m2 = min(64, cnt - c);
            if (tid < m2 * 4) {
                int gi = seg + (int)list[c + (tid >> 2)];
                const float4* src = (const float4*)(sorted_recs + (size_t)gi * 16);
                sp4[tid] = src[tid & 3];
            }
            __syncthreads();

            bool dead = (T <= TTHR);
            if (!dead) {
                for (int j = 0; j < m2; j++) {
                    const float* p = sp + j * 16;
                    float du = pxf - p[0];
                    float dv = pyf - p[1];
                    float power = -0.5f * (p[2]*du*du + p[4]*dv*dv) - p[3]*du*dv;
                    float ai = fminf(p[5] * expf(fminf(power, 0.0f)), 0.99f);
                    bool eff = (ai >= ATHR) && (T > TTHR);
                    float w = eff ? T * ai : 0.0f;
                    cr  += w * p[7];
                    cg  += w * p[8];
                    cb  += w * p[9];
                    dep += w * p[6];
                    acc += w;
                    cnt_px += eff;
                    T = eff ? T * (1.0f - ai) : T;
                }
            }
            alldead = (bool)__syncthreads_and((T <= TTHR) ? 1 : 0);
        }
        // ensure list/wcnt safe to overwrite: last op above was a barrier,
        // and compaction loop also ends with a barrier when cnt==0.
    }

    int pix = py * W + px;
    int HW = H * W;
    out[pix*3 + 0] = cr;
    out[pix*3 + 1] = cg;
    out[pix*3 + 2] = cb;
    out[HW*3 + pix] = dep / fmaxf(acc, 1e-6f);
    out[HW*4 + pix] = (float)cnt_px;
}

extern "C" void kernel_launch(void* const* d_in, const int* in_sizes, int n_in,
                              void* d_out, int out_size, void* d_ws, size_t ws_size,
                              hipStream_t stream) {
    const float* pc    = (const float*)d_in[0];
    const float* feat  = (const float*)d_in[1];
    const int*   inval = (const int*)d_in[3];
    const float* K     = (const float*)d_in[4];
    const float* qc    = (const float*)d_in[5];
    const float* tc    = (const float*)d_in[6];
    const int*   camH  = (const int*)d_in[7];
    const int*   camW  = (const int*)d_in[8];
    const int*   band  = (const int*)d_in[9];
    float* out = (float*)d_out;

    int N = in_sizes[0] / 3;
    int side = (int)(sqrt((double)(out_size / 5)) + 0.5);
    int H = side, W = side;

    float* recs = (float*)d_ws;
    float* keys = recs + (size_t)N * 16;
    size_t keys_rounded = ((size_t)N + 3) & ~(size_t)3;
    float* sorted_recs = keys + keys_rounded;

    int threads = 256;
    int pblocks = (N + threads - 1) / threads;
    preprocess_kernel<<<pblocks, threads, 0, stream>>>(
        pc, feat, inval, K, qc, tc, camH, camW, band, recs, keys, N);
    sort_scatter_kernel<<<pblocks, threads, 0, stream>>>(keys, recs, sorted_recs, N);

    int tiles = (W / TILE_SZ) * (H / TILE_SZ);
    raster_kernel<<<tiles, threads, 0, stream>>>(sorted_recs, N, camH, camW, out);
}

// Round 3
// 66.532 us; speedup vs baseline: 7.2984x; 1.5820x over previous
//
#include <hip/hip_runtime.h>
#include <math.h>

#define TILE_SZ 16
#define NEARP 0.8f
#define FARP 1000.0f
#define ATHR (1.0f/255.0f)
#define TTHR 0.0001f

// Record layout (16 floats, 64B), float4-aligned groups:
//  [0]=u    [1]=v     [2]=conic_a [3]=conic_b
//  [4]=conic_c [5]=alpha [6]=z    [7]=color_r
//  [8]=color_g [9]=color_b [10]=pad [11]=pad
//  [12]=t0x [13]=t1x  [14]=t0y    [15]=t1y     <- bounds as one float4

__global__ void preprocess_kernel(const float* __restrict__ pc,
                                  const float* __restrict__ feat,
                                  const int* __restrict__ invalid_mask,
                                  const float* __restrict__ K,
                                  const float* __restrict__ qcam,
                                  const float* __restrict__ tcam,
                                  const int* __restrict__ cam_h,
                                  const int* __restrict__ cam_w,
                                  const int* __restrict__ sh_band,
                                  float* __restrict__ recs,
                                  float* __restrict__ keys,
                                  int N)
{
    int i = blockIdx.x * blockDim.x + threadIdx.x;
    if (i >= N) return;

    float fx = K[0], cx = K[2], fy = K[4], cy = K[5];
    int H = cam_h[0], W = cam_w[0];

    float qx = qcam[0], qy = qcam[1], qz = qcam[2], qw = qcam[3];
    float qn = sqrtf(qx*qx + qy*qy + qz*qz + qw*qw);
    qx /= qn; qy /= qn; qz /= qn; qw /= qn;
    float R00 = 1.f-2.f*(qy*qy+qz*qz), R01 = 2.f*(qx*qy-qw*qz), R02 = 2.f*(qx*qz+qw*qy);
    float R10 = 2.f*(qx*qy+qw*qz), R11 = 1.f-2.f*(qx*qx+qz*qz), R12 = 2.f*(qy*qz-qw*qx);
    float R20 = 2.f*(qx*qz-qw*qy), R21 = 2.f*(qy*qz+qw*qx), R22 = 1.f-2.f*(qx*qx+qy*qy);
    float C00 = R00, C01 = R10, C02 = R20;
    float C10 = R01, C11 = R11, C12 = R21;
    float C20 = R02, C21 = R12, C22 = R22;
    float tx = tcam[0], ty = tcam[1], tz = tcam[2];
    float tcx = -(C00*tx + C01*ty + C02*tz);
    float tcy = -(C10*tx + C11*ty + C12*tz);
    float tcz = -(C20*tx + C21*ty + C22*tz);

    float px = pc[i*3+0], py = pc[i*3+1], pz = pc[i*3+2];
    float xc = C00*px + C01*py + C02*pz + tcx;
    float yc = C10*px + C11*py + C12*pz + tcy;
    float zc = C20*px + C21*py + C22*pz + tcz;
    float inv_z = 1.0f / zc;
    float u = fx * xc * inv_z + cx;
    float v = fy * yc * inv_z + cy;

    bool valid = (invalid_mask[i] == 0) && (zc > NEARP) && (zc < FARP)
              && (u > -4.0f*TILE_SZ) && (u < (float)W + 4.0f*TILE_SZ)
              && (v > -4.0f*TILE_SZ) && (v < (float)H + 4.0f*TILE_SZ);

    float q0 = feat[i*56+0], q1 = feat[i*56+1], q2 = feat[i*56+2], q3 = feat[i*56+3];
    float pn = sqrtf(q0*q0 + q1*q1 + q2*q2 + q3*q3);
    q0 /= pn; q1 /= pn; q2 /= pn; q3 /= pn;
    float P00 = 1.f-2.f*(q1*q1+q2*q2), P01 = 2.f*(q0*q1-q3*q2), P02 = 2.f*(q0*q2+q3*q1);
    float P10 = 2.f*(q0*q1+q3*q2), P11 = 1.f-2.f*(q0*q0+q2*q2), P12 = 2.f*(q1*q2-q3*q0);
    float P20 = 2.f*(q0*q2-q3*q1), P21 = 2.f*(q1*q2+q3*q0), P22 = 1.f-2.f*(q0*q0+q1*q1);
    float s0 = expf(feat[i*56+4]), s1 = expf(feat[i*56+5]), s2 = expf(feat[i*56+6]);
    float M00 = P00*s0, M01 = P01*s1, M02 = P02*s2;
    float M10 = P10*s0, M11 = P11*s1, M12 = P12*s2;
    float M20 = P20*s0, M21 = P21*s1, M22 = P22*s2;
    float S00 = M00*M00 + M01*M01 + M02*M02;
    float S01 = M00*M10 + M01*M11 + M02*M12;
    float S02 = M00*M20 + M01*M21 + M02*M22;
    float S11 = M10*M10 + M11*M11 + M12*M12;
    float S12 = M10*M20 + M11*M21 + M12*M22;
    float S22 = M20*M20 + M21*M21 + M22*M22;
    float T00 = C00*S00 + C01*S01 + C02*S02;
    float T01 = C00*S01 + C01*S11 + C02*S12;
    float T02 = C00*S02 + C01*S12 + C02*S22;
    float T10 = C10*S00 + C11*S01 + C12*S02;
    float T11 = C10*S01 + C11*S11 + C12*S12;
    float T12 = C10*S02 + C11*S12 + C12*S22;
    float T20 = C20*S00 + C21*S01 + C22*S02;
    float T21 = C20*S01 + C21*S11 + C22*S12;
    float T22 = C20*S02 + C21*S12 + C22*S22;
    float G00 = T00*C00 + T01*C01 + T02*C02;
    float G01 = T00*C10 + T01*C11 + T02*C12;
    float G02 = T00*C20 + T01*C21 + T02*C22;
    float G11 = T10*C10 + T11*C11 + T12*C12;
    float G12 = T10*C20 + T11*C21 + T12*C22;
    float G22 = T20*C20 + T21*C21 + T22*C22;
    float j00 = fx * inv_z;
    float j02 = -fx * xc * inv_z * inv_z;
    float j11 = fy * inv_z;
    float j12 = -fy * yc * inv_z * inv_z;
    float a0 = j00*G00 + j02*G02;
    float a1 = j00*G01 + j02*G12;
    float a2 = j00*G02 + j02*G22;
    float b1 = j11*G11 + j12*G12;
    float b2 = j11*G12 + j12*G22;
    float cov00 = a0*j00 + a2*j02;
    float cov01 = a1*j11 + a2*j12;
    float cov11 = b1*j11 + b2*j12;

    float A = cov00 + 0.3f;
    float B = cov01;
    float Cc = cov11 + 0.3f;
    float det = fmaxf(A*Cc - B*B, 1e-9f);
    float conic_a = Cc / det;
    float conic_b = -B / det;
    float conic_c = A / det;
    float mid = 0.5f * (A + Cc);
    float lam = mid + sqrtf(fmaxf(mid*mid - det, 1e-9f));
    float radii = ceilf(3.0f * sqrtf(lam));

    float aval = feat[i*56+7];
    float alpha = 1.0f / (1.0f + expf(-aval));

    float dnx = px - tx, dny = py - ty, dnz = pz - tz;
    float dn = sqrtf(dnx*dnx + dny*dny + dnz*dnz);
    float dx = dnx/dn, dy = dny/dn, dz = dnz/dn;
    float xx = dx*dx, yy = dy*dy, zz = dz*dz;
    float xy = dx*dy, yz = dy*dz, xz = dx*dz;
    float basis[16];
    basis[0] = 0.28209479177387814f;
    basis[1] = -0.4886025119029199f * dy;
    basis[2] = 0.4886025119029199f * dz;
    basis[3] = -0.4886025119029199f * dx;
    basis[4] = 1.0925484305920792f * xy;
    basis[5] = -1.0925484305920792f * yz;
    basis[6] = 0.31539156525252005f * (2.f*zz - xx - yy);
    basis[7] = -1.0925484305920792f * xz;
    basis[8] = 0.5462742152960396f * (xx - yy);
    basis[9] = -0.5900435899266435f * dy * (3.f*xx - yy);
    basis[10] = 2.890611442640554f * xy * dz;
    basis[11] = -0.4570457994644658f * dy * (4.f*zz - xx - yy);
    basis[12] = 0.3731763325901154f * dz * (2.f*zz - 3.f*xx - 3.f*yy);
    basis[13] = -0.4570457994644658f * dx * (4.f*zz - xx - yy);
    basis[14] = 1.445305721320277f * dz * (xx - yy);
    basis[15] = -0.5900435899266435f * dx * (xx - 3.f*yy);
    int band = sh_band[0];
    int kc = (band + 1) * (band + 1);
    float c0 = 0.f, c1 = 0.f, c2 = 0.f;
#pragma unroll
    for (int j = 0; j < 16; j++) {
        if (j < kc) {
            c0 += basis[j] * feat[i*56 + 8 + 0*16 + j];
            c1 += basis[j] * feat[i*56 + 8 + 1*16 + j];
            c2 += basis[j] * feat[i*56 + 8 + 2*16 + j];
        }
    }
    c0 = fmaxf(c0 + 0.5f, 0.0f);
    c1 = fmaxf(c1 + 0.5f, 0.0f);
    c2 = fmaxf(c2 + 0.5f, 0.0f);

    float tiles_x = (float)(W / TILE_SZ);
    float tiles_y = (float)(H / TILE_SZ);
    float t0x = fminf(fmaxf(floorf((u - radii) / TILE_SZ), 0.0f), tiles_x - 1.0f);
    float t1x = fminf(fmaxf(floorf((u + radii) / TILE_SZ), 0.0f), tiles_x - 1.0f);
    float t0y = fminf(fmaxf(floorf((v - radii) / TILE_SZ), 0.0f), tiles_y - 1.0f);
    float t1y = fminf(fmaxf(floorf((v + radii) / TILE_SZ), 0.0f), tiles_y - 1.0f);

    if (!valid) {
        t0x = 1e30f; t1x = -1e30f; t0y = 1e30f; t1y = -1e30f;
        alpha = 0.0f;
    }

    float* r = recs + (size_t)i * 16;
    r[0] = u;  r[1] = v;  r[2] = conic_a; r[3] = conic_b;
    r[4] = conic_c; r[5] = alpha; r[6] = zc; r[7] = c0;
    r[8] = c1; r[9] = c2; r[10] = 0.f; r[11] = 0.f;
    r[12] = t0x; r[13] = t1x; r[14] = t0y; r[15] = t1y;

    keys[i] = valid ? zc : INFINITY;
}

// 2D-parallel stable rank: block (ic,jc) compares 256 i's vs 256 LDS j-keys.
// partial[jc*N + i] = #j in chunk jc ranked before i. No atomics, deterministic.
__global__ void rank_kernel(const float* __restrict__ keys,
                            int* __restrict__ partial,
                            int N)
{
    __shared__ float sk[256];
    int ic = blockIdx.x, jc = blockIdx.y;
    int tid = threadIdx.x;
    int i = ic * 256 + tid;
    int jbase = jc * 256;
    int m = min(256, N - jbase);
    if (tid < m) sk[tid] = keys[jbase + tid];
    __syncthreads();
    if (i >= N) return;
    float ki = keys[i];
    int r = 0;
    for (int j = 0; j < m; j++) {
        float kj = sk[j];
        r += (kj < ki) || (kj == ki && (jbase + j) < i);
    }
    partial[jc * N + i] = r;
}

__global__ void scatter_kernel(const int* __restrict__ partial,
                               const float* __restrict__ recs,
                               float* __restrict__ sorted_recs,
                               int N, int nchunks)
{
    int i = blockIdx.x * blockDim.x + threadIdx.x;
    if (i >= N) return;
    int rank = 0;
    for (int c = 0; c < nchunks; c++) rank += partial[c * N + i];
    const float4* src = (const float4*)(recs + (size_t)i * 16);
    float4* dst = (float4*)(sorted_recs + (size_t)rank * 16);
    dst[0] = src[0]; dst[1] = src[1]; dst[2] = src[2]; dst[3] = src[3];
}

// One wave (64 threads) per 8x8 pixel quadrant; 4 blocks per 16x16 tile.
// All compaction is wave-level ballot/popc; no cross-wave coordination.
#define LIST_CAP 2048

__global__ __launch_bounds__(64) void raster_kernel(
        const float* __restrict__ sorted_recs, int N,
        const int* __restrict__ cam_h,
        const int* __restrict__ cam_w,
        float* __restrict__ out)
{
    int W = cam_w[0], H = cam_h[0];
    int tiles_x = W / TILE_SZ;
    int sub = blockIdx.x & 3;
    int tile = blockIdx.x >> 2;
    int bx = tile % tiles_x;
    int by = tile / tiles_x;
    int lane = threadIdx.x;
    int px = bx * TILE_SZ + (sub & 1) * 8 + (lane & 7);
    int py = by * TILE_SZ + (sub >> 1) * 8 + (lane >> 3);
    float pxf = (float)px + 0.5f;
    float pyf = (float)py + 0.5f;
    float txf = (float)bx;
    float tyf = (float)by;

    float T = 1.0f;
    float cr = 0.f, cg = 0.f, cb = 0.f;
    float dep = 0.f, acc = 0.f;
    int cnt_px = 0;

    __shared__ unsigned short list[LIST_CAP];  // 4KB
    __shared__ float sp[64 * 16];              // 4KB staging (64 records)

    bool alldead = false;

    for (int seg = 0; seg < N && !alldead; seg += LIST_CAP) {
        int segN = min(LIST_CAP, N - seg);
        int rounds = (segN + 63) / 64;

        // wave-level order-preserving compaction
        int cnt = 0;
        for (int r = 0; r < rounds; r++) {
            int local = r * 64 + lane;
            int idx = seg + local;
            bool pred = false;
            if (local < segN) {
                float4 b = *(const float4*)(sorted_recs + (size_t)idx * 16 + 12);
                pred = (txf >= b.x) && (txf <= b.y) && (tyf >= b.z) && (tyf <= b.w);
            }
            unsigned long long m = __ballot(pred);
            if (pred) {
                int below = __popcll(m & ((1ull << lane) - 1ull));
                list[cnt + below] = (unsigned short)local;
            }
            cnt += __popcll(m);
        }
        __syncthreads();  // single wave: cheap; orders LDS writes->reads

        for (int c = 0; c < cnt && !alldead; c += 64) {
            int m2 = min(64, cnt - c);
            // linear float4 staging: conflict-free LDS writes
#pragma unroll
            for (int k = 0; k < 4; k++) {
                int f = k * 64 + lane;       // float4 index within staging
                int rsel = f >> 2;
                if (rsel < m2) {
                    int gi = seg + (int)list[c + rsel];
                    ((float4*)sp)[f] =
                        ((const float4*)(sorted_recs + (size_t)gi * 16))[f & 3];
                }
            }
            __syncthreads();

            if (T > TTHR) {
                for (int j = 0; j < m2; j++) {
                    const float* p = sp + j * 16;
                    float du = pxf - p[0];
                    float dv = pyf - p[1];
                    float power = -0.5f * (p[2]*du*du + p[4]*dv*dv) - p[3]*du*dv;
                    float ai = fminf(p[5] * expf(fminf(power, 0.0f)), 0.99f);
                    bool eff = (ai >= ATHR) && (T > TTHR);
                    float w = eff ? T * ai : 0.0f;
                    cr  += w * p[7];
                    cg  += w * p[8];
                    cb  += w * p[9];
                    dep += w * p[6];
                    acc += w;
                    cnt_px += eff;
                    T = eff ? T * (1.0f - ai) : T;
                }
            }
            alldead = __all(T <= TTHR);
            __syncthreads();  // protect sp/list reuse
        }
    }

    int pix = py * W + px;
    int HW = H * W;
    out[pix*3 + 0] = cr;
    out[pix*3 + 1] = cg;
    out[pix*3 + 2] = cb;
    out[HW*3 + pix] = dep / fmaxf(acc, 1e-6f);
    out[HW*4 + pix] = (float)cnt_px;
}

extern "C" void kernel_launch(void* const* d_in, const int* in_sizes, int n_in,
                              void* d_out, int out_size, void* d_ws, size_t ws_size,
                              hipStream_t stream) {
    const float* pc    = (const float*)d_in[0];
    const float* feat  = (const float*)d_in[1];
    const int*   inval = (const int*)d_in[3];
    const float* K     = (const float*)d_in[4];
    const float* qc    = (const float*)d_in[5];
    const float* tc    = (const float*)d_in[6];
    const int*   camH  = (const int*)d_in[7];
    const int*   camW  = (const int*)d_in[8];
    const int*   band  = (const int*)d_in[9];
    float* out = (float*)d_out;

    int N = in_sizes[0] / 3;
    int side = (int)(sqrt((double)(out_size / 5)) + 0.5);
    int H = side, W = side;

    float* recs = (float*)d_ws;
    size_t keys_rounded = ((size_t)N + 3) & ~(size_t)3;
    float* keys = recs + (size_t)N * 16;
    float* sorted_recs = keys + keys_rounded;
    int*   partial = (int*)(sorted_recs + (size_t)N * 16);

    int threads = 256;
    int pblocks = (N + threads - 1) / threads;
    int nchunks = (N + 255) / 256;

    preprocess_kernel<<<pblocks, threads, 0, stream>>>(
        pc, feat, inval, K, qc, tc, camH, camW, band, recs, keys, N);
    rank_kernel<<<dim3(nchunks, nchunks), threads, 0, stream>>>(keys, partial, N);
    scatter_kernel<<<pblocks, threads, 0, stream>>>(partial, recs, sorted_recs, N, nchunks);

    int tiles = (W / TILE_SZ) * (H / TILE_SZ);
    raster_kernel<<<tiles * 4, 64, 0, stream>>>(sorted_recs, N, camH, camW, out);
}

// Round 4
// 55.600 us; speedup vs baseline: 8.7335x; 1.1966x over previous
//
#include <hip/hip_runtime.h>
#include <math.h>

#define TILE_SZ 16
#define NEARP 0.8f
#define FARP 1000.0f
#define ATHR (1.0f/255.0f)
#define TTHR 0.0001f

// Record layout (16 floats, 64B), float4-aligned groups:
//  [0]=u    [1]=v     [2]=conic_a [3]=conic_b
//  [4]=conic_c [5]=alpha [6]=z    [7]=color_r
//  [8]=color_g [9]=color_b [10]=pad [11]=pad
//  [12]=t0x [13]=t1x  [14]=t0y    [15]=t1y     <- bounds as one float4

__global__ void preprocess_kernel(const float* __restrict__ pc,
                                  const float* __restrict__ feat,
                                  const int* __restrict__ invalid_mask,
                                  const float* __restrict__ K,
                                  const float* __restrict__ qcam,
                                  const float* __restrict__ tcam,
                                  const int* __restrict__ cam_h,
                                  const int* __restrict__ cam_w,
                                  const int* __restrict__ sh_band,
                                  float* __restrict__ recs,
                                  float* __restrict__ keys,
                                  int N)
{
    int i = blockIdx.x * blockDim.x + threadIdx.x;
    if (i >= N) return;

    float fx = K[0], cx = K[2], fy = K[4], cy = K[5];
    int H = cam_h[0], W = cam_w[0];

    float qx = qcam[0], qy = qcam[1], qz = qcam[2], qw = qcam[3];
    float qn = sqrtf(qx*qx + qy*qy + qz*qz + qw*qw);
    qx /= qn; qy /= qn; qz /= qn; qw /= qn;
    float R00 = 1.f-2.f*(qy*qy+qz*qz), R01 = 2.f*(qx*qy-qw*qz), R02 = 2.f*(qx*qz+qw*qy);
    float R10 = 2.f*(qx*qy+qw*qz), R11 = 1.f-2.f*(qx*qx+qz*qz), R12 = 2.f*(qy*qz-qw*qx);
    float R20 = 2.f*(qx*qz-qw*qy), R21 = 2.f*(qy*qz+qw*qx), R22 = 1.f-2.f*(qx*qx+qy*qy);
    float C00 = R00, C01 = R10, C02 = R20;
    float C10 = R01, C11 = R11, C12 = R21;
    float C20 = R02, C21 = R12, C22 = R22;
    float tx = tcam[0], ty = tcam[1], tz = tcam[2];
    float tcx = -(C00*tx + C01*ty + C02*tz);
    float tcy = -(C10*tx + C11*ty + C12*tz);
    float tcz = -(C20*tx + C21*ty + C22*tz);

    float px = pc[i*3+0], py = pc[i*3+1], pz = pc[i*3+2];
    float xc = C00*px + C01*py + C02*pz + tcx;
    float yc = C10*px + C11*py + C12*pz + tcy;
    float zc = C20*px + C21*py + C22*pz + tcz;
    float inv_z = 1.0f / zc;
    float u = fx * xc * inv_z + cx;
    float v = fy * yc * inv_z + cy;

    bool valid = (invalid_mask[i] == 0) && (zc > NEARP) && (zc < FARP)
              && (u > -4.0f*TILE_SZ) && (u < (float)W + 4.0f*TILE_SZ)
              && (v > -4.0f*TILE_SZ) && (v < (float)H + 4.0f*TILE_SZ);

    float q0 = feat[i*56+0], q1 = feat[i*56+1], q2 = feat[i*56+2], q3 = feat[i*56+3];
    float pn = sqrtf(q0*q0 + q1*q1 + q2*q2 + q3*q3);
    q0 /= pn; q1 /= pn; q2 /= pn; q3 /= pn;
    float P00 = 1.f-2.f*(q1*q1+q2*q2), P01 = 2.f*(q0*q1-q3*q2), P02 = 2.f*(q0*q2+q3*q1);
    float P10 = 2.f*(q0*q1+q3*q2), P11 = 1.f-2.f*(q0*q0+q2*q2), P12 = 2.f*(q1*q2-q3*q0);
    float P20 = 2.f*(q0*q2-q3*q1), P21 = 2.f*(q1*q2+q3*q0), P22 = 1.f-2.f*(q0*q0+q1*q1);
    float s0 = expf(feat[i*56+4]), s1 = expf(feat[i*56+5]), s2 = expf(feat[i*56+6]);
    float M00 = P00*s0, M01 = P01*s1, M02 = P02*s2;
    float M10 = P10*s0, M11 = P11*s1, M12 = P12*s2;
    float M20 = P20*s0, M21 = P21*s1, M22 = P22*s2;
    float S00 = M00*M00 + M01*M01 + M02*M02;
    float S01 = M00*M10 + M01*M11 + M02*M12;
    float S02 = M00*M20 + M01*M21 + M02*M22;
    float S11 = M10*M10 + M11*M11 + M12*M12;
    float S12 = M10*M20 + M11*M21 + M12*M22;
    float S22 = M20*M20 + M21*M21 + M22*M22;
    float T00 = C00*S00 + C01*S01 + C02*S02;
    float T01 = C00*S01 + C01*S11 + C02*S12;
    float T02 = C00*S02 + C01*S12 + C02*S22;
    float T10 = C10*S00 + C11*S01 + C12*S02;
    float T11 = C10*S01 + C11*S11 + C12*S12;
    float T12 = C10*S02 + C11*S12 + C12*S22;
    float T20 = C20*S00 + C21*S01 + C22*S02;
    float T21 = C20*S01 + C21*S11 + C22*S12;
    float T22 = C20*S02 + C21*S12 + C22*S22;
    float G00 = T00*C00 + T01*C01 + T02*C02;
    float G01 = T00*C10 + T01*C11 + T02*C12;
    float G02 = T00*C20 + T01*C21 + T02*C22;
    float G11 = T10*C10 + T11*C11 + T12*C12;
    float G12 = T10*C20 + T11*C21 + T12*C22;
    float G22 = T20*C20 + T21*C21 + T22*C22;
    float j00 = fx * inv_z;
    float j02 = -fx * xc * inv_z * inv_z;
    float j11 = fy * inv_z;
    float j12 = -fy * yc * inv_z * inv_z;
    float a0 = j00*G00 + j02*G02;
    float a1 = j00*G01 + j02*G12;
    float a2 = j00*G02 + j02*G22;
    float b1 = j11*G11 + j12*G12;
    float b2 = j11*G12 + j12*G22;
    float cov00 = a0*j00 + a2*j02;
    float cov01 = a1*j11 + a2*j12;
    float cov11 = b1*j11 + b2*j12;

    float A = cov00 + 0.3f;
    float B = cov01;
    float Cc = cov11 + 0.3f;
    float det = fmaxf(A*Cc - B*B, 1e-9f);
    float conic_a = Cc / det;
    float conic_b = -B / det;
    float conic_c = A / det;
    float mid = 0.5f * (A + Cc);
    float lam = mid + sqrtf(fmaxf(mid*mid - det, 1e-9f));
    float radii = ceilf(3.0f * sqrtf(lam));

    float aval = feat[i*56+7];
    float alpha = 1.0f / (1.0f + expf(-aval));

    float dnx = px - tx, dny = py - ty, dnz = pz - tz;
    float dn = sqrtf(dnx*dnx + dny*dny + dnz*dnz);
    float dx = dnx/dn, dy = dny/dn, dz = dnz/dn;
    float xx = dx*dx, yy = dy*dy, zz = dz*dz;
    float xy = dx*dy, yz = dy*dz, xz = dx*dz;
    float basis[16];
    basis[0] = 0.28209479177387814f;
    basis[1] = -0.4886025119029199f * dy;
    basis[2] = 0.4886025119029199f * dz;
    basis[3] = -0.4886025119029199f * dx;
    basis[4] = 1.0925484305920792f * xy;
    basis[5] = -1.0925484305920792f * yz;
    basis[6] = 0.31539156525252005f * (2.f*zz - xx - yy);
    basis[7] = -1.0925484305920792f * xz;
    basis[8] = 0.5462742152960396f * (xx - yy);
    basis[9] = -0.5900435899266435f * dy * (3.f*xx - yy);
    basis[10] = 2.890611442640554f * xy * dz;
    basis[11] = -0.4570457994644658f * dy * (4.f*zz - xx - yy);
    basis[12] = 0.3731763325901154f * dz * (2.f*zz - 3.f*xx - 3.f*yy);
    basis[13] = -0.4570457994644658f * dx * (4.f*zz - xx - yy);
    basis[14] = 1.445305721320277f * dz * (xx - yy);
    basis[15] = -0.5900435899266435f * dx * (xx - 3.f*yy);
    int band = sh_band[0];
    int kc = (band + 1) * (band + 1);
    float c0 = 0.f, c1 = 0.f, c2 = 0.f;
#pragma unroll
    for (int j = 0; j < 16; j++) {
        if (j < kc) {
            c0 += basis[j] * feat[i*56 + 8 + 0*16 + j];
            c1 += basis[j] * feat[i*56 + 8 + 1*16 + j];
            c2 += basis[j] * feat[i*56 + 8 + 2*16 + j];
        }
    }
    c0 = fmaxf(c0 + 0.5f, 0.0f);
    c1 = fmaxf(c1 + 0.5f, 0.0f);
    c2 = fmaxf(c2 + 0.5f, 0.0f);

    float tiles_x = (float)(W / TILE_SZ);
    float tiles_y = (float)(H / TILE_SZ);
    float t0x = fminf(fmaxf(floorf((u - radii) / TILE_SZ), 0.0f), tiles_x - 1.0f);
    float t1x = fminf(fmaxf(floorf((u + radii) / TILE_SZ), 0.0f), tiles_x - 1.0f);
    float t0y = fminf(fmaxf(floorf((v - radii) / TILE_SZ), 0.0f), tiles_y - 1.0f);
    float t1y = fminf(fmaxf(floorf((v + radii) / TILE_SZ), 0.0f), tiles_y - 1.0f);

    if (!valid) {
        t0x = 1e30f; t1x = -1e30f; t0y = 1e30f; t1y = -1e30f;
        alpha = 0.0f;
    }

    float* r = recs + (size_t)i * 16;
    r[0] = u;  r[1] = v;  r[2] = conic_a; r[3] = conic_b;
    r[4] = conic_c; r[5] = alpha; r[6] = zc; r[7] = c0;
    r[8] = c1; r[9] = c2; r[10] = 0.f; r[11] = 0.f;
    r[12] = t0x; r[13] = t1x; r[14] = t0y; r[15] = t1y;

    keys[i] = valid ? zc : INFINITY;
}

// 2D-parallel stable rank: block (ic,jc) compares 256 i's vs 256 LDS j-keys.
__global__ void rank_kernel(const float* __restrict__ keys,
                            int* __restrict__ partial,
                            int N)
{
    __shared__ float sk[256];
    int ic = blockIdx.x, jc = blockIdx.y;
    int tid = threadIdx.x;
    int i = ic * 256 + tid;
    int jbase = jc * 256;
    int m = min(256, N - jbase);
    if (tid < m) sk[tid] = keys[jbase + tid];
    __syncthreads();
    if (i >= N) return;
    float ki = keys[i];
    int r = 0;
    for (int j = 0; j < m; j++) {
        float kj = sk[j];
        r += (kj < ki) || (kj == ki && (jbase + j) < i);
    }
    partial[jc * N + i] = r;
}

__global__ void scatter_kernel(const int* __restrict__ partial,
                               const float* __restrict__ recs,
                               float* __restrict__ sorted_recs,
                               int N, int nchunks)
{
    int i = blockIdx.x * blockDim.x + threadIdx.x;
    if (i >= N) return;
    int rank = 0;
    for (int c = 0; c < nchunks; c++) rank += partial[c * N + i];
    const float4* src = (const float4*)(recs + (size_t)i * 16);
    float4* dst = (float4*)(sorted_recs + (size_t)rank * 16);
    dst[0] = src[0]; dst[1] = src[1]; dst[2] = src[2]; dst[3] = src[3];
}

// Fused per-tile raster: one block (256 threads = 4 waves) per 16x16 tile.
// Wave wv composites its 8x8 quadrant. Membership computed ONCE per tile,
// with batched bound loads and a 2-barrier cross-wave compaction.
// Composite is double-buffered: next chunk's global loads issue before the
// current chunk's composite, landing in the alternate LDS buffer.
#define LIST_CAP 2048

__global__ __launch_bounds__(256) void raster_kernel(
        const float* __restrict__ sorted_recs, int N,
        const int* __restrict__ cam_h,
        const int* __restrict__ cam_w,
        float* __restrict__ out)
{
    int W = cam_w[0], H = cam_h[0];
    int tiles_x = W / TILE_SZ;
    int bx = blockIdx.x % tiles_x;
    int by = blockIdx.x / tiles_x;
    int tid = threadIdx.x;
    int lane = tid & 63;
    int wv = tid >> 6;
    int px = bx * TILE_SZ + (wv & 1) * 8 + (lane & 7);
    int py = by * TILE_SZ + (wv >> 1) * 8 + (lane >> 3);
    float pxf = (float)px + 0.5f;
    float pyf = (float)py + 0.5f;
    float txf = (float)bx;
    float tyf = (float)by;

    float T = 1.0f;
    float cr = 0.f, cg = 0.f, cbl = 0.f;
    float dep = 0.f, acc = 0.f;
    int cnt_px = 0;

    __shared__ unsigned short list[LIST_CAP];   // 4KB
    __shared__ float sp[2][64 * 16];            // 8KB double-buffered staging
    __shared__ int cntmat[32];                  // (round, wave) member counts

    bool alldead = false;

    for (int seg = 0; seg < N && !alldead; seg += LIST_CAP) {
        int segN = min(LIST_CAP, N - seg);
        int rounds = (segN + 255) >> 8;         // <= 8

        // ---- Phase A: batched bound loads (independent, pipelined) ----
        float4 bnd[8];
#pragma unroll
        for (int r = 0; r < 8; r++) {
            int local = (r << 8) + tid;
            if (r < rounds && local < segN) {
                bnd[r] = *(const float4*)(sorted_recs + (size_t)(seg + local) * 16 + 12);
            } else {
                bnd[r].x = 1e30f; bnd[r].y = -1e30f; bnd[r].z = 1e30f; bnd[r].w = -1e30f;
            }
        }
        unsigned pmask = 0;
#pragma unroll
        for (int r = 0; r < 8; r++) {
            bool pred = (txf >= bnd[r].x) && (txf <= bnd[r].y)
                     && (tyf >= bnd[r].z) && (tyf <= bnd[r].w);
            pmask |= ((unsigned)pred) << r;
        }
#pragma unroll
        for (int r = 0; r < 8; r++) {
            unsigned long long m = __ballot((pmask >> r) & 1u);
            if (lane == 0) cntmat[r * 4 + wv] = __popcll(m);
        }
        __syncthreads();

        // ---- Phase B: register prefix over 32 cells, then compacted writes ----
        int base[8];
        int total = 0;
#pragma unroll
        for (int k = 0; k < 32; k++) {
            if ((k & 3) == wv) base[k >> 2] = total;
            total += cntmat[k];
        }
        int cnt = total;
#pragma unroll
        for (int r = 0; r < 8; r++) {
            bool pred = (pmask >> r) & 1u;
            unsigned long long m = __ballot(pred);
            if (pred) {
                int below = __popcll(m & ((1ull << lane) - 1ull));
                list[base[r] + below] = (unsigned short)((r << 8) + tid);
            }
        }
        __syncthreads();

        // ---- Phase C: double-buffered chunked composite ----
        // prologue: stage chunk 0 into sp[0]
        {
            int m0 = min(64, cnt);
            if (tid < m0 * 4) {
                int gi = seg + (int)list[tid >> 2];
                // LDS byte addr = tid*16 -> linear, conflict-free
                *(float4*)&sp[0][(tid >> 2) * 16 + (tid & 3) * 4] =
                    ((const float4*)(sorted_recs + (size_t)gi * 16))[tid & 3];
            }
        }
        __syncthreads();

        int buf = 0;
        for (int c = 0; c < cnt && !alldead; c += 64) {
            int m2 = min(64, cnt - c);
            int mn = min(64, cnt - (c + 64));

            // issue next-chunk loads early (T14: latency hides under composite)
            float4 nxt; bool have = false;
            if (mn > 0 && tid < mn * 4) {
                int gi = seg + (int)list[c + 64 + (tid >> 2)];
                nxt = ((const float4*)(sorted_recs + (size_t)gi * 16))[tid & 3];
                have = true;
            }

            // composite current chunk from LDS (broadcast reads)
            if (!__all(T <= TTHR)) {
                const float* spb = sp[buf];
                for (int j = 0; j < m2; j++) {
                    float4 p0 = *(const float4*)(spb + j * 16);
                    float4 p1 = *(const float4*)(spb + j * 16 + 4);
                    float4 p2 = *(const float4*)(spb + j * 16 + 8);
                    float du = pxf - p0.x;
                    float dv = pyf - p0.y;
                    float power = -0.5f * (p0.z*du*du + p1.x*dv*dv) - p0.w*du*dv;
                    float ai = fminf(p1.y * expf(fminf(power, 0.0f)), 0.99f);
                    bool eff = (ai >= ATHR) && (T > TTHR);
                    float w = eff ? T * ai : 0.0f;
                    cr  += w * p1.w;
                    cg  += w * p2.x;
                    cbl += w * p2.y;
                    dep += w * p1.z;
                    acc += w;
                    cnt_px += eff;
                    T = eff ? T * (1.0f - ai) : T;
                }
            }

            alldead = (bool)__syncthreads_and((T <= TTHR) ? 1 : 0);
            if (alldead) break;

            if (have) {
                *(float4*)&sp[buf ^ 1][(tid >> 2) * 16 + (tid & 3) * 4] = nxt;
            }
            __syncthreads();
            buf ^= 1;
        }
    }

    int pix = py * W + px;
    int HW = H * W;
    out[pix*3 + 0] = cr;
    out[pix*3 + 1] = cg;
    out[pix*3 + 2] = cbl;
    out[HW*3 + pix] = dep / fmaxf(acc, 1e-6f);
    out[HW*4 + pix] = (float)cnt_px;
}

extern "C" void kernel_launch(void* const* d_in, const int* in_sizes, int n_in,
                              void* d_out, int out_size, void* d_ws, size_t ws_size,
                              hipStream_t stream) {
    const float* pc    = (const float*)d_in[0];
    const float* feat  = (const float*)d_in[1];
    const int*   inval = (const int*)d_in[3];
    const float* K     = (const float*)d_in[4];
    const float* qc    = (const float*)d_in[5];
    const float* tc    = (const float*)d_in[6];
    const int*   camH  = (const int*)d_in[7];
    const int*   camW  = (const int*)d_in[8];
    const int*   band  = (const int*)d_in[9];
    float* out = (float*)d_out;

    int N = in_sizes[0] / 3;
    int side = (int)(sqrt((double)(out_size / 5)) + 0.5);
    int H = side, W = side;

    float* recs = (float*)d_ws;
    size_t keys_rounded = ((size_t)N + 3) & ~(size_t)3;
    float* keys = recs + (size_t)N * 16;
    float* sorted_recs = keys + keys_rounded;
    int*   partial = (int*)(sorted_recs + (size_t)N * 16);

    int threads = 256;
    int pblocks = (N + threads - 1) / threads;
    int nchunks = (N + 255) / 256;

    preprocess_kernel<<<pblocks, threads, 0, stream>>>(
        pc, feat, inval, K, qc, tc, camH, camW, band, recs, keys, N);
    rank_kernel<<<dim3(nchunks, nchunks), threads, 0, stream>>>(keys, partial, N);
    scatter_kernel<<<pblocks, threads, 0, stream>>>(partial, recs, sorted_recs, N, nchunks);

    int tiles = (W / TILE_SZ) * (H / TILE_SZ);
    raster_kernel<<<tiles, 256, 0, stream>>>(sorted_recs, N, camH, camW, out);
}